// Round 1
// baseline (1178.651 us; speedup 1.0000x reference)
//
#include <hip/hip_runtime.h>

#define TOKENS 32768
#define DIMD 384
#define HID 1536
#define NE 4
#define BM 64
#define BH 128

typedef __bf16 bf16;
typedef bf16 bf16x8 __attribute__((ext_vector_type(8)));
typedef float f32x4 __attribute__((ext_vector_type(4)));

__device__ __forceinline__ unsigned short f2bf(float f) {
  unsigned u = __builtin_bit_cast(unsigned, f);
  u += 0x7fffu + ((u >> 16) & 1u);
  return (unsigned short)(u >> 16);
}

// exact-gelu via tanh form: gelu(v) = v * sigmoid(1.59577*(v + 0.044715 v^3))
// max abs deviation from erf-gelu ~4e-4, far below the 5.7e-2 threshold.
__device__ __forceinline__ float gelu_f(float v) {
  float u2 = 1.5957691216057308f * v * (1.0f + 0.044715f * v * v);
  return v / (1.0f + __expf(-u2));
}

// ---------------- transpose + fp32->bf16 convert ----------------
// src: fp32 [E][R][C]  ->  dst: bf16(ushort) [E][C][R]
__global__ __launch_bounds__(256) void transpose_cvt_kernel(
    const float* __restrict__ src, unsigned short* __restrict__ dst,
    int R, int C) {
  __shared__ float tile[32][33];
  int e = blockIdx.z;
  const float* s = src + (size_t)e * R * C;
  unsigned short* d = dst + (size_t)e * R * C;
  int c0 = blockIdx.x * 32, r0 = blockIdx.y * 32;
  int tx = threadIdx.x, ty = threadIdx.y;  // (32, 8)
#pragma unroll
  for (int i = 0; i < 32; i += 8)
    tile[ty + i][tx] = s[(size_t)(r0 + ty + i) * C + (c0 + tx)];
  __syncthreads();
#pragma unroll
  for (int i = 0; i < 32; i += 8)
    d[(size_t)(c0 + ty + i) * R + (r0 + tx)] = f2bf(tile[tx][ty + i]);
}

// ---------------- gating: fp32 scores, softmax, top-2, renorm ----------------
__global__ __launch_bounds__(256) void gate_kernel(
    const float* __restrict__ x, const float* __restrict__ gw,
    const float* __restrict__ gb, float* __restrict__ wgt) {
  int lane = threadIdx.x & 63;
  int token = blockIdx.x * 4 + (threadIdx.x >> 6);
  const float* xr = x + (size_t)token * DIMD;
  float s0 = 0.f, s1 = 0.f, s2 = 0.f, s3 = 0.f;
  for (int i = lane; i < DIMD; i += 64) {
    float xv = xr[i];
    float4 g = *(const float4*)(gw + i * 4);
    s0 = fmaf(xv, g.x, s0); s1 = fmaf(xv, g.y, s1);
    s2 = fmaf(xv, g.z, s2); s3 = fmaf(xv, g.w, s3);
  }
#pragma unroll
  for (int m = 32; m >= 1; m >>= 1) {
    s0 += __shfl_xor(s0, m); s1 += __shfl_xor(s1, m);
    s2 += __shfl_xor(s2, m); s3 += __shfl_xor(s3, m);
  }
  if (lane == 0) {
    float sc[4] = { s0 + gb[0], s1 + gb[1], s2 + gb[2], s3 + gb[3] };
    float mx = fmaxf(fmaxf(sc[0], sc[1]), fmaxf(sc[2], sc[3]));
    float p[4]; float z = 0.f;
#pragma unroll
    for (int e = 0; e < 4; ++e) { p[e] = __expf(sc[e] - mx); z += p[e]; }
#pragma unroll
    for (int e = 0; e < 4; ++e) p[e] /= z;
    int i1 = 0;
#pragma unroll
    for (int e = 1; e < 4; ++e) if (p[e] > p[i1]) i1 = e;
    int i2 = -1;
#pragma unroll
    for (int e = 0; e < 4; ++e) if (e != i1 && (i2 < 0 || p[e] > p[i2])) i2 = e;
    float denom = p[i1] + p[i2] + 1e-9f;
    float w[4] = {0.f, 0.f, 0.f, 0.f};
    w[i1] = p[i1] / denom;
    w[i2] = p[i2] / denom;
    float4 wv = { w[0], w[1], w[2], w[3] };
    *(float4*)(wgt + token * 4) = wv;
  }
}

// ---------------- fused dense MoE FFN ----------------
// grid 512, block 256 (4 waves). per-wg out tile: 64 tokens x 384.
__global__ __launch_bounds__(256, 2) void moe_ffn_kernel(
    const float* __restrict__ x, const unsigned short* __restrict__ w1t,
    const unsigned short* __restrict__ w2t, const float* __restrict__ b1,
    const float* __restrict__ b2, const float* __restrict__ wgt,
    float* __restrict__ out) {
  __shared__ unsigned short xs[BM * DIMD];  // 48 KiB, XOR-swizzled
  __shared__ unsigned short hs[BM * BH];    // 16 KiB, XOR-swizzled
  const int tid = threadIdx.x;
  const int wid = tid >> 6;
  const int lane = tid & 63;
  const int lhi = lane >> 4;   // 0..3
  const int llo = lane & 15;   // 0..15
  const int t0 = blockIdx.x * BM;
  const int wm = wid >> 1, wn = wid & 1;

  // stage x tile: fp32 -> bf16, swizzled store. 6144 float4 over 256 threads.
#pragma unroll
  for (int i = 0; i < 24; ++i) {
    int idx4 = i * 256 + tid;
    int m = idx4 / 96;              // 96 float4 per row
    int kq = idx4 - m * 96;
    const float4 v = *(const float4*)(x + (size_t)(t0 + m) * DIMD + kq * 4);
    ushort4 h4;
    h4.x = f2bf(v.x); h4.y = f2bf(v.y); h4.z = f2bf(v.z); h4.w = f2bf(v.w);
    int byte = ((m * DIMD + kq * 4) * 2) ^ ((m & 7) << 4);
    *(ushort4*)((char*)xs + byte) = h4;
  }
  __syncthreads();

  f32x4 acc2[4][6] = {};  // rows 16*mt.., cols 96*wid + 16*nt + llo

  for (int e = 0; e < NE; ++e) {
    // routing weights for the 8 hs-rows this lane writes
    float wrow[8];
#pragma unroll
    for (int mi = 0; mi < 2; ++mi)
#pragma unroll
      for (int r = 0; r < 4; ++r)
        wrow[mi * 4 + r] = wgt[(t0 + 32 * wm + 16 * mi + 4 * lhi + r) * 4 + e];

    for (int hc = 0; hc < HID / BH; ++hc) {
      const int hh = hc * BH;
      // ---- GEMM1: H[32wm..+32][64wn..+64] over K=384 ----
      f32x4 acc1[2][4] = {};
      const unsigned short* w1p =
          w1t + ((size_t)e * HID + hh + 64 * wn + llo) * DIMD + 8 * lhi;
      for (int ks = 0; ks < DIMD / 32; ++ks) {
        bf16x8 a[2];
#pragma unroll
        for (int mi = 0; mi < 2; ++mi) {
          int m = 32 * wm + 16 * mi + llo;
          int byte = ((m * DIMD + 32 * ks + 8 * lhi) * 2) ^ ((m & 7) << 4);
          a[mi] = *(const bf16x8*)((const char*)xs + byte);
        }
#pragma unroll
        for (int nf = 0; nf < 4; ++nf) {
          bf16x8 b = *(const bf16x8*)(w1p + (size_t)(16 * nf) * DIMD + 32 * ks);
#pragma unroll
          for (int mi = 0; mi < 2; ++mi)
            acc1[mi][nf] = __builtin_amdgcn_mfma_f32_16x16x32_bf16(
                a[mi], b, acc1[mi][nf], 0, 0, 0);
        }
      }
      // ---- gelu + routing-weight scale -> hs (bf16, swizzled) ----
      __syncthreads();  // previous chunk's GEMM2 readers are done with hs
#pragma unroll
      for (int mi = 0; mi < 2; ++mi) {
#pragma unroll
        for (int nf = 0; nf < 4; ++nf) {
          float b1v = b1[e * HID + hh + 64 * wn + 16 * nf + llo];
#pragma unroll
          for (int r = 0; r < 4; ++r) {
            int m = 32 * wm + 16 * mi + 4 * lhi + r;
            int k = 64 * wn + 16 * nf + llo;
            float hv = gelu_f(acc1[mi][nf][r] + b1v) * wrow[mi * 4 + r];
            int byte = ((m * BH + k) * 2) ^ ((m & 7) << 4);
            *(unsigned short*)((char*)hs + byte) = f2bf(hv);
          }
        }
      }
      __syncthreads();
      // ---- GEMM2: acc2 += hs[64][128] @ w2T cols [96*wid .. +96] ----
      const unsigned short* w2p =
          w2t + ((size_t)e * DIMD + 96 * wid + llo) * HID + hh + 8 * lhi;
      for (int ks2 = 0; ks2 < BH / 32; ++ks2) {
        bf16x8 a2[4];
#pragma unroll
        for (int mt = 0; mt < 4; ++mt) {
          int m = 16 * mt + llo;
          int byte = ((m * BH + 32 * ks2 + 8 * lhi) * 2) ^ ((m & 7) << 4);
          a2[mt] = *(const bf16x8*)((const char*)hs + byte);
        }
#pragma unroll
        for (int nt = 0; nt < 6; ++nt) {
          bf16x8 b = *(const bf16x8*)(w2p + (size_t)(16 * nt) * HID + 32 * ks2);
#pragma unroll
          for (int mt = 0; mt < 4; ++mt)
            acc2[mt][nt] = __builtin_amdgcn_mfma_f32_16x16x32_bf16(
                a2[mt], b, acc2[mt][nt], 0, 0, 0);
        }
      }
    }
  }

  // ---- epilogue: add bias mix, store fp32 ----
  float b2v[6][4];
#pragma unroll
  for (int nt = 0; nt < 6; ++nt)
#pragma unroll
    for (int e2 = 0; e2 < 4; ++e2)
      b2v[nt][e2] = b2[e2 * DIMD + 96 * wid + 16 * nt + llo];

#pragma unroll
  for (int mt = 0; mt < 4; ++mt) {
#pragma unroll
    for (int r = 0; r < 4; ++r) {
      int t = t0 + 16 * mt + 4 * lhi + r;
      const float4 wv = *(const float4*)(wgt + t * 4);
#pragma unroll
      for (int nt = 0; nt < 6; ++nt) {
        float bias = wv.x * b2v[nt][0] + wv.y * b2v[nt][1] +
                     wv.z * b2v[nt][2] + wv.w * b2v[nt][3];
        out[(size_t)t * DIMD + 96 * wid + 16 * nt + llo] = acc2[mt][nt][r] + bias;
      }
    }
  }
}

extern "C" void kernel_launch(void* const* d_in, const int* in_sizes, int n_in,
                              void* d_out, int out_size, void* d_ws, size_t ws_size,
                              hipStream_t stream) {
  (void)in_sizes; (void)n_in; (void)out_size; (void)ws_size;
  const float* x  = (const float*)d_in[0];
  const float* gw = (const float*)d_in[1];
  const float* gb = (const float*)d_in[2];
  const float* w1 = (const float*)d_in[3];
  const float* b1 = (const float*)d_in[4];
  const float* w2 = (const float*)d_in[5];
  const float* b2 = (const float*)d_in[6];
  float* out = (float*)d_out;

  // ws layout: w1t bf16 [4][1536][384] | w2t bf16 [4][384][1536] | wgt f32 [32768][4]
  unsigned short* w1t = (unsigned short*)d_ws;
  unsigned short* w2t = w1t + (size_t)NE * HID * DIMD;
  float* wgt = (float*)(w2t + (size_t)NE * HID * DIMD);

  transpose_cvt_kernel<<<dim3(HID / 32, DIMD / 32, NE), dim3(32, 8), 0, stream>>>(
      w1, w1t, DIMD, HID);
  transpose_cvt_kernel<<<dim3(DIMD / 32, HID / 32, NE), dim3(32, 8), 0, stream>>>(
      w2, w2t, HID, DIMD);
  gate_kernel<<<TOKENS / 4, 256, 0, stream>>>(x, gw, gb, wgt);
  moe_ffn_kernel<<<TOKENS / BM, 256, 0, stream>>>(x, w1t, w2t, b1, b2, wgt, out);
}